// Round 4
// baseline (447.338 us; speedup 1.0000x reference)
//
#include <hip/hip_runtime.h>
#include <hip/hip_bf16.h>
#include <hip/hip_cooperative_groups.h>

namespace cg = cooperative_groups;

#define AS1 __attribute__((address_space(1)))
#define AS3 __attribute__((address_space(3)))

typedef __attribute__((ext_vector_type(8))) short bfrag8;   // 8 bf16 in 4 VGPRs
typedef __attribute__((ext_vector_type(4))) float floatx4;  // MFMA accumulator

static constexpr int M = 4096, N = 4096, K = 4096;
static constexpr long long NELEM = 16777216LL;   // 4096*4096 (both x and W)
static constexpr int CB = 512;                   // cooperative blocks (2/CU — co-residency safe)
// threads = CB*256 = 131072 ; float4 per array per thread = 4194304/131072 = 32

// ---------- round-to-nearest-even fp32 -> bf16 ----------
__device__ __forceinline__ unsigned short f2bf(float f) {
    unsigned int u = __float_as_uint(f);
    u += 0x7FFFu + ((u >> 16) & 1u);
    return (unsigned short)(u >> 16);
}

// ---------- ternary quantize: bf16 {-1,0,+1}; keep R1-R3's exact fp32 division ----------
__device__ __forceinline__ unsigned short tq(float v, float scale_f) {
    float wn = v / scale_f;
    if (fabsf(wn) > 0.5f)
        return (unsigned short)(0x3F80u | ((__float_as_uint(v) >> 16) & 0x8000u));
    return 0;
}

// ---------- dual block reduce (double); result returned to ALL threads ----------
__device__ __forceinline__ void block_reduce2(double& a, double& b) {
    #pragma unroll
    for (int off = 32; off > 0; off >>= 1) {
        a += __shfl_down(a, off, 64);
        b += __shfl_down(b, off, 64);
    }
    __shared__ double pa[4], pb[4];
    int lane = threadIdx.x & 63, wv = threadIdx.x >> 6;
    __syncthreads();                       // protect pa/pb reuse
    if (lane == 0) { pa[wv] = a; pb[wv] = b; }
    __syncthreads();
    a = pa[0] + pa[1] + pa[2] + pa[3];
    b = pb[0] + pb[1] + pb[2] + pb[3];
}

// ---------- single cooperative prep: reduce |x|,|w| + x->bf16 ; sync ; quantize w ----------
__global__ __launch_bounds__(256, 2) void prep_coop(
        const float* __restrict__ x, unsigned short* __restrict__ xb,
        const float* __restrict__ w, unsigned short* __restrict__ qb,
        double* __restrict__ px, double* __restrict__ pw,
        float* __restrict__ scales) {
    cg::grid_group grid = cg::this_grid();
    const long long t = (long long)blockIdx.x * 256 + threadIdx.x;
    const long long T = (long long)CB * 256;        // 131072

    const float4* x4 = (const float4*)x;
    const float4* w4 = (const float4*)w;
    ushort4* xb4 = (ushort4*)xb;

    double sx = 0.0, sw = 0.0;
    // --- phase 1a: |x| reduce + bf16 convert (32 float4, chunks of 8) ---
    #pragma unroll
    for (int c = 0; c < 4; c++) {
        float4 v[8];
        #pragma unroll
        for (int i = 0; i < 8; i++) v[i] = x4[t + (c * 8 + i) * T];
        #pragma unroll
        for (int i = 0; i < 8; i++) {
            sx += (double)fabsf(v[i].x); sx += (double)fabsf(v[i].y);
            sx += (double)fabsf(v[i].z); sx += (double)fabsf(v[i].w);
        }
        #pragma unroll
        for (int i = 0; i < 8; i++) {
            ushort4 r;
            r.x = f2bf(v[i].x); r.y = f2bf(v[i].y);
            r.z = f2bf(v[i].z); r.w = f2bf(v[i].w);
            xb4[t + (c * 8 + i) * T] = r;
        }
    }
    // --- phase 1b: |w| reduce ---
    #pragma unroll
    for (int c = 0; c < 4; c++) {
        float4 v[8];
        #pragma unroll
        for (int i = 0; i < 8; i++) v[i] = w4[t + (c * 8 + i) * T];
        #pragma unroll
        for (int i = 0; i < 8; i++) {
            sw += (double)fabsf(v[i].x); sw += (double)fabsf(v[i].y);
            sw += (double)fabsf(v[i].z); sw += (double)fabsf(v[i].w);
        }
    }
    block_reduce2(sx, sw);
    if (threadIdx.x == 0) { px[blockIdx.x] = sx; pw[blockIdx.x] = sw; }
    __threadfence();
    grid.sync();

    // --- phase 2: every block redundantly folds the 512 partials (identical tree) ---
    double fx = px[threadIdx.x] + px[threadIdx.x + 256];
    double fw = pw[threadIdx.x] + pw[threadIdx.x + 256];
    block_reduce2(fx, fw);
    const float scale_w = (float)fmax(fw / (double)NELEM, 1e-8);
    const float scale_x = (float)fmax(fx / (double)NELEM, 1e-8);
    if (blockIdx.x == 0 && threadIdx.x == 0) {
        scales[0] = scale_w; scales[1] = scale_x;
    }

    // --- phase 3: quantize w (L3-hot second read) ---
    ushort4* q4 = (ushort4*)qb;
    #pragma unroll
    for (int c = 0; c < 4; c++) {
        float4 v[8];
        #pragma unroll
        for (int i = 0; i < 8; i++) v[i] = w4[t + (c * 8 + i) * T];
        #pragma unroll
        for (int i = 0; i < 8; i++) {
            ushort4 r;
            r.x = tq(v[i].x, scale_w); r.y = tq(v[i].y, scale_w);
            r.z = tq(v[i].z, scale_w); r.w = tq(v[i].w, scale_w);
            q4[t + (c * 8 + i) * T] = r;
        }
    }
}

// ---------- m97-style bf16 GEMM with XOR-swizzled LDS (unchanged from R2/R3) ----------
// out[m][n] = (sum_k A[m][k]*B[n][k]) * wscale + bias[n]*iscale
// LDS row r (128B) holds its 8 k-chunks permuted: chunk j at slot j^(r&7).
// Staging permutes the *global* source per lane; reads apply the inverse.
// SQ_LDS_BANK_CONFLICT = 0 verified (R2/R3).
__global__ __launch_bounds__(256) void gemm_bt(
        const unsigned short* __restrict__ A,
        const unsigned short* __restrict__ B,
        const float* __restrict__ bias,
        const float* __restrict__ scales,   // [0]=wscale, [1]=iscale
        float* __restrict__ out) {
    __shared__ unsigned short lds[2 * 128 * 64];  // A tile 16KB + B tile 16KB
    const char* ldsA = (const char*)lds;
    const char* ldsB = (const char*)lds + 16384;

    const int tid = threadIdx.x;
    const int lane = tid & 63;
    const int wv = tid >> 6;            // wave 0..3
    const int wm = wv & 1;              // 2x2 wave grid, 64x64 each
    const int wn = wv >> 1;
    const int col16 = lane & 15;
    const int quad = lane >> 4;

    const int m0 = blockIdx.y * 128;
    const int n0 = blockIdx.x * 128;

    const int srow = lane >> 3;                      // 0..7 within chunk
    const int scol = ((lane & 7) ^ srow) * 8;        // swizzled k-offset (elements)

    floatx4 acc[4][4];
    #pragma unroll
    for (int i = 0; i < 4; i++)
        #pragma unroll
        for (int j = 0; j < 4; j++)
            acc[i][j] = (floatx4)0.0f;

    for (int k0 = 0; k0 < K; k0 += 64) {
        #pragma unroll
        for (int j = 0; j < 4; j++) {
            const int c = wv * 4 + j;            // 0..15
            const int row = c * 8 + srow;        // 0..127
            const unsigned short* ga = A + (size_t)(m0 + row) * K + k0 + scol;
            const unsigned short* gb = B + (size_t)(n0 + row) * K + k0 + scol;
            char* la = (char*)lds + c * 1024 + lane * 16;
            char* lb = (char*)lds + 16384 + c * 1024 + lane * 16;
            __builtin_amdgcn_global_load_lds((const AS1 void*)ga, (AS3 void*)la, 16, 0, 0);
            __builtin_amdgcn_global_load_lds((const AS1 void*)gb, (AS3 void*)lb, 16, 0, 0);
        }
        __syncthreads();

        #pragma unroll
        for (int kk = 0; kk < 64; kk += 32) {
            const int kc = (kk >> 3) + quad;             // k-chunk index 0..7
            const int sw = (kc ^ (col16 & 7)) << 4;      // swizzled byte offset in row
            bfrag8 af[4], bfr[4];
            #pragma unroll
            for (int i = 0; i < 4; i++) {
                const int ra = wm * 64 + i * 16 + col16;
                const int rb = wn * 64 + i * 16 + col16;
                af[i]  = *(const bfrag8*)(ldsA + ra * 128 + sw);
                bfr[i] = *(const bfrag8*)(ldsB + rb * 128 + sw);
            }
            #pragma unroll
            for (int i = 0; i < 4; i++)
                #pragma unroll
                for (int j = 0; j < 4; j++)
                    acc[i][j] = __builtin_amdgcn_mfma_f32_16x16x32_bf16(af[i], bfr[j], acc[i][j], 0, 0, 0);
        }
        __syncthreads();
    }

    const float wscale = scales[0];
    const float iscale = scales[1];

    float bv[4];
    #pragma unroll
    for (int j = 0; j < 4; j++)
        bv[j] = bias[n0 + wn * 64 + j * 16 + col16] * iscale;

    #pragma unroll
    for (int i = 0; i < 4; i++) {
        const int mbase = m0 + wm * 64 + i * 16 + quad * 4;
        #pragma unroll
        for (int j = 0; j < 4; j++) {
            const int n = n0 + wn * 64 + j * 16 + col16;
            #pragma unroll
            for (int r = 0; r < 4; r++)
                out[(size_t)(mbase + r) * N + n] = acc[i][j][r] * wscale + bv[j];
        }
    }
}

extern "C" void kernel_launch(void* const* d_in, const int* in_sizes, int n_in,
                              void* d_out, int out_size, void* d_ws, size_t ws_size,
                              hipStream_t stream) {
    const float* x    = (const float*)d_in[0];   // (2,2048,4096) fp32
    const float* w    = (const float*)d_in[1];   // (4096,4096) fp32
    const float* bias = (const float*)d_in[2];   // (4096,) fp32
    float* out = (float*)d_out;                  // (2,2048,4096) fp32

    // ws layout (same 64MB+16KB footprint as R2/R3):
    char* ws = (char*)d_ws;
    float*  scales = (float*)ws;                             // 8 B
    double* px     = (double*)(ws + 256);                    // 512 doubles (4 KB)
    double* pw     = (double*)(ws + 256 + CB * 8);           // 512 doubles (4 KB)
    unsigned short* xb = (unsigned short*)(ws + 16384);                      // 32 MB bf16 x
    unsigned short* qb = (unsigned short*)(ws + 16384 + (size_t)NELEM * 2);  // 32 MB bf16 qW

    {
        const float* ax = x; unsigned short* axb = xb;
        const float* aw = w; unsigned short* aqb = qb;
        double* apx = px; double* apw = pw; float* asc = scales;
        void* args[] = { (void*)&ax, (void*)&axb, (void*)&aw, (void*)&aqb,
                         (void*)&apx, (void*)&apw, (void*)&asc };
        hipLaunchCooperativeKernel((const void*)prep_coop, dim3(CB), dim3(256),
                                   args, 0, stream);
    }

    dim3 grid(N / 128, M / 128);
    gemm_bt<<<grid, 256, 0, stream>>>(xb, qb, bias, scales, out);
}

// Round 5
// 328.059 us; speedup vs baseline: 1.3636x; 1.3636x over previous
//
#include <hip/hip_runtime.h>
#include <hip/hip_bf16.h>

#define AS1 __attribute__((address_space(1)))
#define AS3 __attribute__((address_space(3)))

typedef __attribute__((ext_vector_type(8))) short bfrag8;   // 8 bf16 in 4 VGPRs
typedef __attribute__((ext_vector_type(4))) float floatx4;  // MFMA accumulator

static constexpr int M = 4096, N = 4096, K = 4096;
static constexpr long long NELEM = 16777216LL;   // 4096*4096 (both x and W)
static constexpr int PB = 1024;                  // prep blocks per array
// each prep block owns a contiguous 64 KB span: 4096 float4 = 16 iters x 256 lanes

// ---------- round-to-nearest-even fp32 -> bf16 ----------
__device__ __forceinline__ unsigned short f2bf(float f) {
    unsigned int u = __float_as_uint(f);
    u += 0x7FFFu + ((u >> 16) & 1u);
    return (unsigned short)(u >> 16);
}

// ---------- ternary quantize: bf16 {-1,0,+1}; exact fp32 division as reference ----------
__device__ __forceinline__ unsigned short tq(float v, float scale_f) {
    float wn = v / scale_f;
    if (fabsf(wn) > 0.5f)
        return (unsigned short)(0x3F80u | ((__float_as_uint(v) >> 16) & 0x8000u));
    return 0;
}

// ---------- block reduce (double) -> value on thread 0 ----------
__device__ __forceinline__ double block_reduce(double s) {
    #pragma unroll
    for (int off = 32; off > 0; off >>= 1) s += __shfl_down(s, off, 64);
    __shared__ double part[4];
    int lane = threadIdx.x & 63, wv = threadIdx.x >> 6;
    if (lane == 0) part[wv] = s;
    __syncthreads();
    return part[0] + part[1] + part[2] + part[3];
}

// ---------- dual block reduce (double), broadcast result to ALL threads ----------
__device__ __forceinline__ void block_reduce2_bcast(double& a, double& b) {
    #pragma unroll
    for (int off = 32; off > 0; off >>= 1) {
        a += __shfl_down(a, off, 64);
        b += __shfl_down(b, off, 64);
    }
    __shared__ double pa[4], pb[4];
    int lane = threadIdx.x & 63, wv = threadIdx.x >> 6;
    if (lane == 0) { pa[wv] = a; pb[wv] = b; }
    __syncthreads();
    a = pa[0] + pa[1] + pa[2] + pa[3];
    b = pb[0] + pb[1] + pb[2] + pb[3];
}

// ---------- prep: blocks [0,PB) -> sum|x| + x->bf16 ; [PB,2PB) -> sum|w| ----------
// Block-contiguous spans (m146-style): block rb streams 64 KB of contiguous data,
// iterating 4 KB per step. (R1-R4 used grid-wide 8MB strides -> ~1 TB/s; testing
// the contiguity theory.)
__global__ __launch_bounds__(256) void prep_reduce(
        const float* __restrict__ x, unsigned short* __restrict__ xb,
        const float* __restrict__ w,
        double* __restrict__ px, double* __restrict__ pw) {
    const int b = blockIdx.x;
    const bool isW = b >= PB;
    const int rb = isW ? b - PB : b;
    const float4* src = (const float4*)(isW ? w : x);
    const long long base = (long long)rb * 4096 + threadIdx.x;  // float4 index

    float4 v[16];
    #pragma unroll
    for (int i = 0; i < 16; i++) v[i] = src[base + i * 256];    // 16 independent loads

    double s = 0.0;
    #pragma unroll
    for (int i = 0; i < 16; i++) {
        s += (double)fabsf(v[i].x); s += (double)fabsf(v[i].y);
        s += (double)fabsf(v[i].z); s += (double)fabsf(v[i].w);
    }

    if (!isW) {
        ushort4* xb4 = (ushort4*)xb;
        #pragma unroll
        for (int i = 0; i < 16; i++) {
            ushort4 r;
            r.x = f2bf(v[i].x); r.y = f2bf(v[i].y);
            r.z = f2bf(v[i].z); r.w = f2bf(v[i].w);
            xb4[base + i * 256] = r;
        }
    }

    double bs = block_reduce(s);
    if (threadIdx.x == 0) (isW ? pw : px)[rb] = bs;
}

// ---------- quantize w (block-contiguous) + inline scale finalize ----------
// Every block redundantly folds the 1024+1024 partials with an identical
// deterministic tree (same value in every block); block 0 stores scales[].
__global__ __launch_bounds__(256) void quantize_w(
        const float* __restrict__ w, unsigned short* __restrict__ qb,
        const double* __restrict__ px, const double* __restrict__ pw,
        float* __restrict__ scales) {
    const int t = threadIdx.x;
    double sx = 0.0, sw = 0.0;
    #pragma unroll
    for (int i = 0; i < 4; i++) { sx += px[t + i * 256]; sw += pw[t + i * 256]; }
    block_reduce2_bcast(sx, sw);
    const float scale_w = (float)fmax(sw / (double)NELEM, 1e-8);
    const float scale_x = (float)fmax(sx / (double)NELEM, 1e-8);
    if (blockIdx.x == 0 && t == 0) { scales[0] = scale_w; scales[1] = scale_x; }

    const float4* w4 = (const float4*)w;
    ushort4* q4 = (ushort4*)qb;
    const long long base = (long long)blockIdx.x * 4096 + t;
    float4 v[16];
    #pragma unroll
    for (int i = 0; i < 16; i++) v[i] = w4[base + i * 256];
    #pragma unroll
    for (int i = 0; i < 16; i++) {
        ushort4 r;
        r.x = tq(v[i].x, scale_w); r.y = tq(v[i].y, scale_w);
        r.z = tq(v[i].z, scale_w); r.w = tq(v[i].w, scale_w);
        q4[base + i * 256] = r;
    }
}

// ---------- m97-style bf16 GEMM with XOR-swizzled LDS (unchanged since R2) ----------
// out[m][n] = (sum_k A[m][k]*B[n][k]) * wscale + bias[n]*iscale
// LDS row r (128B) holds its 8 k-chunks permuted: chunk j at slot j^(r&7).
// SQ_LDS_BANK_CONFLICT = 0 verified (R2/R3).
__global__ __launch_bounds__(256) void gemm_bt(
        const unsigned short* __restrict__ A,
        const unsigned short* __restrict__ B,
        const float* __restrict__ bias,
        const float* __restrict__ scales,   // [0]=wscale, [1]=iscale
        float* __restrict__ out) {
    __shared__ unsigned short lds[2 * 128 * 64];  // A tile 16KB + B tile 16KB
    const char* ldsA = (const char*)lds;
    const char* ldsB = (const char*)lds + 16384;

    const int tid = threadIdx.x;
    const int lane = tid & 63;
    const int wv = tid >> 6;            // wave 0..3
    const int wm = wv & 1;              // 2x2 wave grid, 64x64 each
    const int wn = wv >> 1;
    const int col16 = lane & 15;
    const int quad = lane >> 4;

    const int m0 = blockIdx.y * 128;
    const int n0 = blockIdx.x * 128;

    const int srow = lane >> 3;                      // 0..7 within chunk
    const int scol = ((lane & 7) ^ srow) * 8;        // swizzled k-offset (elements)

    floatx4 acc[4][4];
    #pragma unroll
    for (int i = 0; i < 4; i++)
        #pragma unroll
        for (int j = 0; j < 4; j++)
            acc[i][j] = (floatx4)0.0f;

    for (int k0 = 0; k0 < K; k0 += 64) {
        #pragma unroll
        for (int j = 0; j < 4; j++) {
            const int c = wv * 4 + j;            // 0..15
            const int row = c * 8 + srow;        // 0..127
            const unsigned short* ga = A + (size_t)(m0 + row) * K + k0 + scol;
            const unsigned short* gb = B + (size_t)(n0 + row) * K + k0 + scol;
            char* la = (char*)lds + c * 1024 + lane * 16;
            char* lb = (char*)lds + 16384 + c * 1024 + lane * 16;
            __builtin_amdgcn_global_load_lds((const AS1 void*)ga, (AS3 void*)la, 16, 0, 0);
            __builtin_amdgcn_global_load_lds((const AS1 void*)gb, (AS3 void*)lb, 16, 0, 0);
        }
        __syncthreads();

        #pragma unroll
        for (int kk = 0; kk < 64; kk += 32) {
            const int kc = (kk >> 3) + quad;             // k-chunk index 0..7
            const int sw = (kc ^ (col16 & 7)) << 4;      // swizzled byte offset in row
            bfrag8 af[4], bfr[4];
            #pragma unroll
            for (int i = 0; i < 4; i++) {
                const int ra = wm * 64 + i * 16 + col16;
                const int rb = wn * 64 + i * 16 + col16;
                af[i]  = *(const bfrag8*)(ldsA + ra * 128 + sw);
                bfr[i] = *(const bfrag8*)(ldsB + rb * 128 + sw);
            }
            #pragma unroll
            for (int i = 0; i < 4; i++)
                #pragma unroll
                for (int j = 0; j < 4; j++)
                    acc[i][j] = __builtin_amdgcn_mfma_f32_16x16x32_bf16(af[i], bfr[j], acc[i][j], 0, 0, 0);
        }
        __syncthreads();
    }

    const float wscale = scales[0];
    const float iscale = scales[1];

    float bv[4];
    #pragma unroll
    for (int j = 0; j < 4; j++)
        bv[j] = bias[n0 + wn * 64 + j * 16 + col16] * iscale;

    #pragma unroll
    for (int i = 0; i < 4; i++) {
        const int mbase = m0 + wm * 64 + i * 16 + quad * 4;
        #pragma unroll
        for (int j = 0; j < 4; j++) {
            const int n = n0 + wn * 64 + j * 16 + col16;
            #pragma unroll
            for (int r = 0; r < 4; r++)
                out[(size_t)(mbase + r) * N + n] = acc[i][j][r] * wscale + bv[j];
        }
    }
}

extern "C" void kernel_launch(void* const* d_in, const int* in_sizes, int n_in,
                              void* d_out, int out_size, void* d_ws, size_t ws_size,
                              hipStream_t stream) {
    const float* x    = (const float*)d_in[0];   // (2,2048,4096) fp32
    const float* w    = (const float*)d_in[1];   // (4096,4096) fp32
    const float* bias = (const float*)d_in[2];   // (4096,) fp32
    float* out = (float*)d_out;                  // (2,2048,4096) fp32

    // ws layout (fits R1-proven floor of 16 KB + 64 MB):
    char* ws = (char*)d_ws;
    float*  scales = (float*)ws;                       // 16 B
    double* px     = (double*)(ws + 256);              // 1024 doubles (8 KB)
    double* pw     = (double*)(ws + 256 + PB * 8);     // 1024 doubles (8 KB)
    unsigned short* xb = (unsigned short*)(ws + 16640);                      // 32 MB bf16 x
    unsigned short* qb = (unsigned short*)(ws + 16640 + (size_t)NELEM * 2);  // 32 MB bf16 qW

    prep_reduce<<<2 * PB, 256, 0, stream>>>(x, xb, w, px, pw);
    quantize_w<<<PB, 256, 0, stream>>>(w, qb, px, pw, scales);

    dim3 grid(N / 128, M / 128);
    gemm_bt<<<grid, 256, 0, stream>>>(xb, qb, bias, scales, out);
}